// Round 1
// baseline (3295.530 us; speedup 1.0000x reference)
//
#include <hip/hip_runtime.h>

typedef _Float16 f16;
typedef _Float16 half8 __attribute__((ext_vector_type(8)));

#define BATCH 4

// ---------------- weight transpose: w[co][ci][27] -> wT[co][27][ci] ----------------
__global__ void transpose_w_k(const float* __restrict__ w, float* __restrict__ wT,
                              int COUT, int CIN) {
  int idx = blockIdx.x * 256 + threadIdx.x;
  int total = COUT * CIN * 27;
  if (idx >= total) return;
  int k = idx % 27;
  int t = idx / 27;
  int ci = t % CIN;
  int co = t / CIN;
  wT[((size_t)co * 27 + k) * CIN + ci] = w[idx];
}

// ---------------- mask dilation, stride 1, from int mask (active = mask<1) ----------------
__global__ __launch_bounds__(256) void dilate_s1_k(const int* __restrict__ mask,
                                                   unsigned char* __restrict__ mo) {
  const int D = 64, D3 = D * D * D;
  int v = blockIdx.x * 256 + threadIdx.x;
  int b = blockIdx.y;
  int ow = v & 63, t = v >> 6, oh = t & 63, od = t >> 6;
  const int* mb = mask + (size_t)b * D3;
  int act = 0;
  for (int kd = -1; kd <= 1; kd++) { int id = od + kd; if ((unsigned)id >= (unsigned)D) continue;
    for (int kh = -1; kh <= 1; kh++) { int ih = oh + kh; if ((unsigned)ih >= (unsigned)D) continue;
      for (int kw = -1; kw <= 1; kw++) { int iw = ow + kw; if ((unsigned)iw >= (unsigned)D) continue;
        act |= (mb[((size_t)id * D + ih) * D + iw] < 1) ? 1 : 0;
      } } }
  mo[(size_t)b * D3 + v] = (unsigned char)act;
}

// ---------------- mask dilation, stride 2, u8 -> u8 ----------------
template<int DIN, int DOUT>
__global__ __launch_bounds__(256) void dilate_s2_k(const unsigned char* __restrict__ mi,
                                                   unsigned char* __restrict__ mo) {
  const int Do3 = DOUT * DOUT * DOUT;
  int v = blockIdx.x * 256 + threadIdx.x;
  if (v >= Do3) return;
  int b = blockIdx.y;
  int ow = v % DOUT, t = v / DOUT, oh = t % DOUT, od = t / DOUT;
  const unsigned char* ib = mi + (size_t)b * DIN * DIN * DIN;
  int act = 0;
  for (int kd = 0; kd < 3; kd++) { int id = od * 2 - 1 + kd; if ((unsigned)id >= (unsigned)DIN) continue;
    for (int kh = 0; kh < 3; kh++) { int ih = oh * 2 - 1 + kh; if ((unsigned)ih >= (unsigned)DIN) continue;
      for (int kw = 0; kw < 3; kw++) { int iw = ow * 2 - 1 + kw; if ((unsigned)iw >= (unsigned)DIN) continue;
        act |= ib[((size_t)id * DIN + ih) * DIN + iw];
      } } }
  mo[(size_t)b * Do3 + v] = (unsigned char)(act ? 1 : 0);
}

// ---------------- conv1: x[B][3][64^3] fp32 (masked) -> h1[B][64^3][64] fp16 ----------------
__global__ __launch_bounds__(256) void conv1_k(const float* __restrict__ x,
                                               const int* __restrict__ mask,
                                               const float* __restrict__ w,   // [64][3][27]
                                               const float* __restrict__ bias,
                                               const unsigned char* __restrict__ mo, // m1
                                               f16* __restrict__ out) {
  const int D = 64, D3 = D * D * D, COUT = 64, CHUNK = 16;
  int v = blockIdx.x * 256 + threadIdx.x;
  int co0 = blockIdx.y * CHUNK;
  int b = blockIdx.z;
  size_t outOff = ((size_t)b * D3 + v) * COUT + co0;
  if (!mo[(size_t)b * D3 + v]) {
    #pragma unroll
    for (int c = 0; c < CHUNK; c++) out[outOff + c] = (f16)0.f;
    return;
  }
  int ow = v & 63, t = v >> 6, oh = t & 63, od = t >> 6;
  float acc[CHUNK];
  #pragma unroll
  for (int c = 0; c < CHUNK; c++) acc[c] = 0.f;
  const int* mb = mask + (size_t)b * D3;
  const float* xb = x + (size_t)b * 3 * D3;
  for (int kd = 0; kd < 3; kd++) { int id = od - 1 + kd; if ((unsigned)id >= (unsigned)D) continue;
    for (int kh = 0; kh < 3; kh++) { int ih = oh - 1 + kh; if ((unsigned)ih >= (unsigned)D) continue;
      for (int kw = 0; kw < 3; kw++) { int iw = ow - 1 + kw; if ((unsigned)iw >= (unsigned)D) continue;
        size_t sp = ((size_t)id * D + ih) * D + iw;
        if (mb[sp] >= 1) continue;  // inactive input voxel contributes zero
        int k = (kd * 3 + kh) * 3 + kw;
        #pragma unroll
        for (int ci = 0; ci < 3; ci++) {
          float xv = xb[(size_t)ci * D3 + sp];
          #pragma unroll
          for (int c = 0; c < CHUNK; c++)
            acc[c] = fmaf(w[((size_t)(co0 + c) * 3 + ci) * 27 + k], xv, acc[c]);
        }
      } } }
  #pragma unroll
  for (int c = 0; c < CHUNK; c++) {
    float r = acc[c] + bias[co0 + c];
    out[outOff + c] = (f16)(r > 0.f ? r : 0.f);
  }
}

// ---------------- generic channel-last conv, stride 2 ----------------
// in:  [B][DIN^3][CIN] fp16, wT: [COUT][27][CIN] fp32, out: [B][DOUT^3][COUT] fp16
template<int CIN, int DIN, int DOUT, int CHUNK>
__global__ __launch_bounds__(256) void conv_cl_k(const f16* __restrict__ in,
                                                 const float* __restrict__ wT,
                                                 const float* __restrict__ bias,
                                                 const unsigned char* __restrict__ mo,
                                                 f16* __restrict__ out, int COUT) {
  const int Do3 = DOUT * DOUT * DOUT;
  int v = blockIdx.x * 256 + threadIdx.x;
  if (v >= Do3) return;
  int co0 = blockIdx.y * CHUNK;
  int b = blockIdx.z;
  size_t outOff = ((size_t)b * Do3 + v) * COUT + co0;
  if (!mo[(size_t)b * Do3 + v]) {
    #pragma unroll
    for (int c = 0; c < CHUNK; c++) out[outOff + c] = (f16)0.f;
    return;
  }
  int ow = v % DOUT, t = v / DOUT, oh = t % DOUT, od = t / DOUT;
  float acc[CHUNK];
  #pragma unroll
  for (int c = 0; c < CHUNK; c++) acc[c] = 0.f;
  const f16* ib = in + (size_t)b * DIN * DIN * DIN * CIN;
  const float* wb = wT + (size_t)co0 * 27 * CIN;
  for (int kd = 0; kd < 3; kd++) { int id = od * 2 - 1 + kd; if ((unsigned)id >= (unsigned)DIN) continue;
    for (int kh = 0; kh < 3; kh++) { int ih = oh * 2 - 1 + kh; if ((unsigned)ih >= (unsigned)DIN) continue;
      for (int kw = 0; kw < 3; kw++) { int iw = ow * 2 - 1 + kw; if ((unsigned)iw >= (unsigned)DIN) continue;
        int k = (kd * 3 + kh) * 3 + kw;
        const f16* ip = ib + (((size_t)id * DIN + ih) * DIN + iw) * CIN;
        const float* wk = wb + (size_t)k * CIN;
        for (int ci = 0; ci < CIN; ci += 8) {
          half8 hv = *reinterpret_cast<const half8*>(ip + ci);
          #pragma unroll
          for (int j = 0; j < 8; j++) {
            float xv = (float)hv[j];
            #pragma unroll
            for (int c = 0; c < CHUNK; c++)
              acc[c] = fmaf(wk[(size_t)c * 27 * CIN + ci + j], xv, acc[c]);
          }
        }
      } } }
  #pragma unroll
  for (int c = 0; c < CHUNK; c++) {
    float r = acc[c] + bias[co0 + c];
    out[outOff + c] = (f16)(r > 0.f ? r : 0.f);
  }
}

// ---------------- max pool over spatial + leaky relu ----------------
__global__ __launch_bounds__(512) void pool_k(const f16* __restrict__ h4, float* __restrict__ outp) {
  int co = threadIdx.x;          // 512 channels
  int b = blockIdx.x;
  const f16* p = h4 + (size_t)b * 512 * 512 + co;
  float m = 0.f;                 // all h4 values are >= 0 (relu or masked 0)
  for (int v = 0; v < 512; v++) m = fmaxf(m, (float)p[(size_t)v * 512]);
  float r = (m >= 0.f) ? m : 0.2f * m;
  outp[b * 512 + co] = r;
}

extern "C" void kernel_launch(void* const* d_in, const int* in_sizes, int n_in,
                              void* d_out, int out_size, void* d_ws, size_t ws_size,
                              hipStream_t stream) {
  const float* x    = (const float*)d_in[0];
  const int*   mask = (const int*)d_in[1];
  const float* w1 = (const float*)d_in[2];
  const float* b1 = (const float*)d_in[3];
  const float* w2 = (const float*)d_in[4];
  const float* b2 = (const float*)d_in[5];
  const float* w3 = (const float*)d_in[6];
  const float* b3 = (const float*)d_in[7];
  const float* w4 = (const float*)d_in[8];
  const float* b4 = (const float*)d_in[9];
  float* outp = (float*)d_out;

  char* ws = (char*)d_ws;
  size_t off = 0;
  auto alloc = [&](size_t bytes) -> char* {
    char* p = ws + off;
    off = (off + bytes + 255) & ~(size_t)255;
    return p;
  };
  float* wt2 = (float*)alloc((size_t)128 * 64 * 27 * 4);
  float* wt3 = (float*)alloc((size_t)256 * 128 * 27 * 4);
  float* wt4 = (float*)alloc((size_t)512 * 256 * 27 * 4);
  unsigned char* m1 = (unsigned char*)alloc((size_t)BATCH * 262144);
  unsigned char* m2 = (unsigned char*)alloc((size_t)BATCH * 32768);
  unsigned char* m3 = (unsigned char*)alloc((size_t)BATCH * 4096);
  unsigned char* m4 = (unsigned char*)alloc((size_t)BATCH * 512);
  f16* h1 = (f16*)alloc((size_t)BATCH * 262144 * 64 * 2);
  f16* h2 = (f16*)alloc((size_t)BATCH * 32768 * 128 * 2);
  f16* h3 = (f16*)alloc((size_t)BATCH * 4096 * 256 * 2);
  f16* h4 = (f16*)alloc((size_t)BATCH * 512 * 512 * 2);
  if (off > ws_size) return;  // workspace too small -> clean (visible) failure

  // weight transposes
  transpose_w_k<<<dim3((128 * 64 * 27 + 255) / 256), 256, 0, stream>>>(w2, wt2, 128, 64);
  transpose_w_k<<<dim3((256 * 128 * 27 + 255) / 256), 256, 0, stream>>>(w3, wt3, 256, 128);
  transpose_w_k<<<dim3((512 * 256 * 27 + 255) / 256), 256, 0, stream>>>(w4, wt4, 512, 256);

  // mask pyramid
  dilate_s1_k<<<dim3(1024, BATCH), 256, 0, stream>>>(mask, m1);
  dilate_s2_k<64, 32><<<dim3(128, BATCH), 256, 0, stream>>>(m1, m2);
  dilate_s2_k<32, 16><<<dim3(16, BATCH), 256, 0, stream>>>(m2, m3);
  dilate_s2_k<16, 8><<<dim3(2, BATCH), 256, 0, stream>>>(m3, m4);

  // conv blocks
  conv1_k<<<dim3(1024, 4, BATCH), 256, 0, stream>>>(x, mask, w1, b1, m1, h1);
  conv_cl_k<64, 64, 32, 16><<<dim3(128, 8, BATCH), 256, 0, stream>>>(h1, wt2, b2, m2, h2, 128);
  conv_cl_k<128, 32, 16, 16><<<dim3(16, 16, BATCH), 256, 0, stream>>>(h2, wt3, b3, m3, h3, 256);
  conv_cl_k<256, 16, 8, 16><<<dim3(2, 32, BATCH), 256, 0, stream>>>(h3, wt4, b4, m4, h4, 512);

  // spatial max pool + leaky relu
  pool_k<<<dim3(BATCH), 512, 0, stream>>>(h4, outp);
}

// Round 2
// 574.835 us; speedup vs baseline: 5.7330x; 5.7330x over previous
//
#include <hip/hip_runtime.h>

typedef _Float16 f16;
typedef _Float16 half8 __attribute__((ext_vector_type(8)));
typedef float f32x4 __attribute__((ext_vector_type(4)));

#define BATCH 4

// ===================== weight prep =====================
// generic: w[co][ci][27] f32 -> w27[k][co][ci] f16
__global__ __launch_bounds__(256) void wprep_k(const float* __restrict__ w,
                                               f16* __restrict__ w27, int COUT, int CIN) {
  int idx = blockIdx.x * 256 + threadIdx.x;
  int total = COUT * CIN * 27;
  if (idx >= total) return;
  int k = idx % 27;
  int t = idx / 27;
  int ci = t % CIN;
  int co = t / CIN;
  w27[((size_t)k * COUT + co) * CIN + ci] = (f16)w[idx];
}

// conv1: w[64][3][27] f32 -> w1f[co][96] f16, q = ci*32 + k (k>=27 zero-padded)
__global__ __launch_bounds__(256) void wprep1_k(const float* __restrict__ w,
                                                f16* __restrict__ wf) {
  int idx = blockIdx.x * 256 + threadIdx.x;   // 64*96
  if (idx >= 64 * 96) return;
  int q = idx % 96, co = idx / 96;
  int ci = q >> 5, k = q & 31;
  float v = (k < 27) ? w[(co * 3 + ci) * 27 + k] : 0.f;
  wf[idx] = (f16)v;
}

// xmh[b][ci][v] = mask-active ? x : 0, as f16
__global__ __launch_bounds__(256) void xmask_k(const float* __restrict__ x,
                                               const int* __restrict__ mask,
                                               f16* __restrict__ xmh) {
  const int D3 = 262144;
  int idx = blockIdx.x * 256 + threadIdx.x;   // B*3*D3
  if (idx >= BATCH * 3 * D3) return;
  int v = idx % D3;
  int b = idx / (3 * D3);
  bool act = mask[(size_t)b * D3 + v] < 1;
  xmh[idx] = act ? (f16)x[idx] : (f16)0.f;
}

// ===================== mask pyramid =====================
__global__ __launch_bounds__(256) void dilate_s1_k(const int* __restrict__ mask,
                                                   unsigned char* __restrict__ mo) {
  const int D = 64, D3 = D * D * D;
  int v = blockIdx.x * 256 + threadIdx.x;
  int b = blockIdx.y;
  int ow = v & 63, t = v >> 6, oh = t & 63, od = t >> 6;
  const int* mb = mask + (size_t)b * D3;
  int act = 0;
  for (int kd = -1; kd <= 1; kd++) { int id = od + kd; if ((unsigned)id >= (unsigned)D) continue;
    for (int kh = -1; kh <= 1; kh++) { int ih = oh + kh; if ((unsigned)ih >= (unsigned)D) continue;
      for (int kw = -1; kw <= 1; kw++) { int iw = ow + kw; if ((unsigned)iw >= (unsigned)D) continue;
        act |= (mb[((size_t)id * D + ih) * D + iw] < 1) ? 1 : 0;
      } } }
  mo[(size_t)b * D3 + v] = (unsigned char)act;
}

template<int DIN, int DOUT>
__global__ __launch_bounds__(256) void dilate_s2_k(const unsigned char* __restrict__ mi,
                                                   unsigned char* __restrict__ mo) {
  const int Do3 = DOUT * DOUT * DOUT;
  int v = blockIdx.x * 256 + threadIdx.x;
  if (v >= Do3) return;
  int b = blockIdx.y;
  int ow = v % DOUT, t = v / DOUT, oh = t % DOUT, od = t / DOUT;
  const unsigned char* ib = mi + (size_t)b * DIN * DIN * DIN;
  int act = 0;
  for (int kd = 0; kd < 3; kd++) { int id = od * 2 - 1 + kd; if ((unsigned)id >= (unsigned)DIN) continue;
    for (int kh = 0; kh < 3; kh++) { int ih = oh * 2 - 1 + kh; if ((unsigned)ih >= (unsigned)DIN) continue;
      for (int kw = 0; kw < 3; kw++) { int iw = ow * 2 - 1 + kw; if ((unsigned)iw >= (unsigned)DIN) continue;
        act |= ib[((size_t)id * DIN + ih) * DIN + iw];
      } } }
  mo[(size_t)b * Do3 + v] = (unsigned char)(act ? 1 : 0);
}

// ===================== conv1 via MFMA =====================
// A = gather(xmh) [BM][96]; B = w1f [64][96] staged once; C = [BM][64]
template<int BM>
__global__ __launch_bounds__(256) void conv1_mfma_k(const f16* __restrict__ xmh,
                                                    const f16* __restrict__ w1f,
                                                    const float* __restrict__ bias,
                                                    const unsigned char* __restrict__ mo,
                                                    f16* __restrict__ out) {
  const int D = 64, D3 = D * D * D, COUT = 64;
  constexpr int K = 96, LD = K + 8;
  constexpr int WM = 2, WN = 2;
  constexpr int MF = BM / (16 * WM), NF = 64 / (16 * WN);
  __shared__ __align__(16) f16 As[BM][LD];
  __shared__ __align__(16) f16 Bs[64][LD];

  const int tid = threadIdx.x, lane = tid & 63, wave = tid >> 6;
  const int wm = wave >> 1, wn = wave & 1;
  const int v0 = blockIdx.x * BM;
  const int b = blockIdx.y;
  const f16* xb = xmh + (size_t)b * 3 * D3;

  // stage B once (coalesced)
  for (int c = tid; c < 64 * (K / 8); c += 256) {
    int row = c / (K / 8), cc = c % (K / 8);
    *reinterpret_cast<half8*>(&Bs[row][cc * 8]) =
        *reinterpret_cast<const half8*>(w1f + row * K + cc * 8);
  }
  // stage A: per-element gather (q = ci*32 + k)
  for (int e = tid; e < BM * K; e += 256) {
    int row = e / K, q = e - row * K;
    int ci = q >> 5, k = q & 31;
    f16 val = (f16)0.f;
    if (k < 27) {
      int kd = k / 9, r2 = k - kd * 9, kh = r2 / 3, kw = r2 - kh * 3;
      int v = v0 + row;
      int ow = v & 63, oh = (v >> 6) & 63, od = v >> 12;
      int id = od - 1 + kd, ih = oh - 1 + kh, iw = ow - 1 + kw;
      if ((unsigned)id < (unsigned)D && (unsigned)ih < (unsigned)D && (unsigned)iw < (unsigned)D)
        val = xb[(size_t)ci * D3 + ((id * D + ih) * D + iw)];
    }
    As[row][q] = val;
  }
  __syncthreads();

  f32x4 acc[MF][NF] = {};
  const int chanoff = (lane >> 4) << 3;
  const int arow = wm * MF * 16 + (lane & 15);
  const int brow = wn * NF * 16 + (lane & 15);
  #pragma unroll
  for (int q0 = 0; q0 < K; q0 += 32) {
    half8 a[MF], bb[NF];
    #pragma unroll
    for (int mf = 0; mf < MF; mf++)
      a[mf] = *reinterpret_cast<const half8*>(&As[arow + mf * 16][q0 + chanoff]);
    #pragma unroll
    for (int nf = 0; nf < NF; nf++)
      bb[nf] = *reinterpret_cast<const half8*>(&Bs[brow + nf * 16][q0 + chanoff]);
    #pragma unroll
    for (int mf = 0; mf < MF; mf++)
      #pragma unroll
      for (int nf = 0; nf < NF; nf++)
        acc[mf][nf] = __builtin_amdgcn_mfma_f32_16x16x32_f16(a[mf], bb[nf], acc[mf][nf], 0, 0, 0);
  }

  // epilogue
  const unsigned char* mb = mo + (size_t)b * D3;
  f16* ob = out + (size_t)b * D3 * COUT;
  float bv[NF];
  #pragma unroll
  for (int nf = 0; nf < NF; nf++) bv[nf] = bias[wn * NF * 16 + nf * 16 + (lane & 15)];
  #pragma unroll
  for (int mf = 0; mf < MF; mf++) {
    #pragma unroll
    for (int r = 0; r < 4; r++) {
      int v = v0 + wm * MF * 16 + mf * 16 + ((lane >> 4) << 2) + r;
      bool act = mb[v] != 0;
      #pragma unroll
      for (int nf = 0; nf < NF; nf++) {
        int co = wn * NF * 16 + nf * 16 + (lane & 15);
        float val = acc[mf][nf][r] + bv[nf];
        val = act ? (val > 0.f ? val : 0.f) : 0.f;
        ob[(size_t)v * COUT + co] = (f16)val;
      }
    }
  }
}

// ===================== generic stride-2 conv via MFMA =====================
// in [B][DIN^3][CIN] f16, w27 [27][COUT][CIN] f16, out [B][DOUT^3][COUT] f16
template<int CIN, int COUT, int DIN, int DOUT, int BM, int BN, int WM, int WN>
__global__ __launch_bounds__(WM * WN * 64) void conv_mfma_k(const f16* __restrict__ in,
                                                            const f16* __restrict__ w27,
                                                            const float* __restrict__ bias,
                                                            const unsigned char* __restrict__ mo,
                                                            f16* __restrict__ out) {
  constexpr int MF = BM / (16 * WM);
  constexpr int NF = BN / (16 * WN);
  constexpr int THREADS = WM * WN * 64;
  constexpr int LD = CIN + 8;
  constexpr int D3o = DOUT * DOUT * DOUT;
  constexpr int LOGD = (DOUT == 32) ? 5 : ((DOUT == 16) ? 4 : 3);

  __shared__ __align__(16) f16 As[BM][LD];
  __shared__ __align__(16) f16 Bs[BN][LD];

  const int tid = threadIdx.x, lane = tid & 63, wave = tid >> 6;
  const int wm = wave / WN, wn = wave % WN;
  const int v0 = blockIdx.x * BM;
  const int co0 = blockIdx.y * BN;
  const int b = blockIdx.z;
  const f16* ib = in + (size_t)b * DIN * DIN * DIN * CIN;

  f32x4 acc[MF][NF] = {};

  const int chanoff = (lane >> 4) << 3;
  const int arow = wm * MF * 16 + (lane & 15);
  const int brow = wn * NF * 16 + (lane & 15);

  for (int k = 0; k < 27; k++) {
    int kd = k / 9, r2 = k - kd * 9, kh = r2 / 3, kw = r2 - kh * 3;
    // stage A (gathered voxel rows)
    constexpr int CA = BM * CIN / 8;
    for (int c = tid; c < CA; c += THREADS) {
      int row = c / (CIN / 8), cc = c & (CIN / 8 - 1);
      int v = v0 + row;
      int ow = v & (DOUT - 1), oh = (v >> LOGD) & (DOUT - 1), od = v >> (2 * LOGD);
      int id = 2 * od - 1 + kd, ih = 2 * oh - 1 + kh, iw = 2 * ow - 1 + kw;
      half8 val = {};
      if ((unsigned)id < (unsigned)DIN && (unsigned)ih < (unsigned)DIN && (unsigned)iw < (unsigned)DIN)
        val = *reinterpret_cast<const half8*>(ib + (((size_t)id * DIN + ih) * DIN + iw) * CIN + cc * 8);
      *reinterpret_cast<half8*>(&As[row][cc * 8]) = val;
    }
    // stage B (k-slice of weights, coalesced)
    const f16* wk = w27 + ((size_t)k * COUT + co0) * CIN;
    constexpr int CB = BN * CIN / 8;
    for (int c = tid; c < CB; c += THREADS) {
      int row = c / (CIN / 8), cc = c & (CIN / 8 - 1);
      *reinterpret_cast<half8*>(&Bs[row][cc * 8]) =
          *reinterpret_cast<const half8*>(wk + (size_t)row * CIN + cc * 8);
    }
    __syncthreads();
    #pragma unroll
    for (int ci0 = 0; ci0 < CIN; ci0 += 32) {
      half8 a[MF], bb[NF];
      #pragma unroll
      for (int mf = 0; mf < MF; mf++)
        a[mf] = *reinterpret_cast<const half8*>(&As[arow + mf * 16][ci0 + chanoff]);
      #pragma unroll
      for (int nf = 0; nf < NF; nf++)
        bb[nf] = *reinterpret_cast<const half8*>(&Bs[brow + nf * 16][ci0 + chanoff]);
      #pragma unroll
      for (int mf = 0; mf < MF; mf++)
        #pragma unroll
        for (int nf = 0; nf < NF; nf++)
          acc[mf][nf] = __builtin_amdgcn_mfma_f32_16x16x32_f16(a[mf], bb[nf], acc[mf][nf], 0, 0, 0);
    }
    __syncthreads();
  }

  // epilogue: mask, bias, relu, store f16
  const unsigned char* mb = mo + (size_t)b * D3o;
  f16* ob = out + (size_t)b * D3o * COUT;
  float bv[NF];
  #pragma unroll
  for (int nf = 0; nf < NF; nf++) bv[nf] = bias[co0 + wn * NF * 16 + nf * 16 + (lane & 15)];
  #pragma unroll
  for (int mf = 0; mf < MF; mf++) {
    #pragma unroll
    for (int r = 0; r < 4; r++) {
      int v = v0 + wm * MF * 16 + mf * 16 + ((lane >> 4) << 2) + r;
      bool act = mb[v] != 0;
      #pragma unroll
      for (int nf = 0; nf < NF; nf++) {
        int co = co0 + wn * NF * 16 + nf * 16 + (lane & 15);
        float val = acc[mf][nf][r] + bv[nf];
        val = act ? (val > 0.f ? val : 0.f) : 0.f;
        ob[(size_t)v * COUT + co] = (f16)val;
      }
    }
  }
}

// ===================== max pool + leaky relu =====================
__global__ __launch_bounds__(256) void pool_k(const f16* __restrict__ h4,
                                              float* __restrict__ outp) {
  __shared__ float red[4][64];
  int b = blockIdx.y;
  int cl = threadIdx.x & 63;
  int co = blockIdx.x * 64 + cl;
  int vg = threadIdx.x >> 6;
  const f16* p = h4 + (size_t)b * 512 * 512;
  float m = 0.f;  // values are relu outputs or exact 0
  for (int v = vg * 128; v < vg * 128 + 128; v++) m = fmaxf(m, (float)p[(size_t)v * 512 + co]);
  red[vg][cl] = m;
  __syncthreads();
  if (threadIdx.x < 64) {
    m = fmaxf(fmaxf(red[0][threadIdx.x], red[1][threadIdx.x]),
              fmaxf(red[2][threadIdx.x], red[3][threadIdx.x]));
    float r = (m >= 0.f) ? m : 0.2f * m;
    outp[b * 512 + blockIdx.x * 64 + threadIdx.x] = r;
  }
}

extern "C" void kernel_launch(void* const* d_in, const int* in_sizes, int n_in,
                              void* d_out, int out_size, void* d_ws, size_t ws_size,
                              hipStream_t stream) {
  const float* x    = (const float*)d_in[0];
  const int*   mask = (const int*)d_in[1];
  const float* w1 = (const float*)d_in[2];
  const float* b1 = (const float*)d_in[3];
  const float* w2 = (const float*)d_in[4];
  const float* b2 = (const float*)d_in[5];
  const float* w3 = (const float*)d_in[6];
  const float* b3 = (const float*)d_in[7];
  const float* w4 = (const float*)d_in[8];
  const float* b4 = (const float*)d_in[9];
  float* outp = (float*)d_out;

  char* ws = (char*)d_ws;
  size_t off = 0;
  auto alloc = [&](size_t bytes) -> char* {
    char* p = ws + off;
    off = (off + bytes + 255) & ~(size_t)255;
    return p;
  };
  f16* wf1 = (f16*)alloc((size_t)64 * 96 * 2);
  f16* wf2 = (f16*)alloc((size_t)27 * 128 * 64 * 2);
  f16* wf3 = (f16*)alloc((size_t)27 * 256 * 128 * 2);
  f16* wf4 = (f16*)alloc((size_t)27 * 512 * 256 * 2);
  f16* xmh = (f16*)alloc((size_t)BATCH * 3 * 262144 * 2);
  unsigned char* m1 = (unsigned char*)alloc((size_t)BATCH * 262144);
  unsigned char* m2 = (unsigned char*)alloc((size_t)BATCH * 32768);
  unsigned char* m3 = (unsigned char*)alloc((size_t)BATCH * 4096);
  unsigned char* m4 = (unsigned char*)alloc((size_t)BATCH * 512);
  f16* h1 = (f16*)alloc((size_t)BATCH * 262144 * 64 * 2);
  f16* h2 = (f16*)alloc((size_t)BATCH * 32768 * 128 * 2);
  f16* h3 = (f16*)alloc((size_t)BATCH * 4096 * 256 * 2);
  f16* h4 = (f16*)alloc((size_t)BATCH * 512 * 512 * 2);
  if (off > ws_size) return;  // workspace too small -> visible failure

  // weight / input prep
  wprep1_k<<<dim3((64 * 96 + 255) / 256), 256, 0, stream>>>(w1, wf1);
  wprep_k<<<dim3((128 * 64 * 27 + 255) / 256), 256, 0, stream>>>(w2, wf2, 128, 64);
  wprep_k<<<dim3((256 * 128 * 27 + 255) / 256), 256, 0, stream>>>(w3, wf3, 256, 128);
  wprep_k<<<dim3((512 * 256 * 27 + 255) / 256), 256, 0, stream>>>(w4, wf4, 512, 256);
  xmask_k<<<dim3((BATCH * 3 * 262144 + 255) / 256), 256, 0, stream>>>(x, mask, xmh);

  // mask pyramid
  dilate_s1_k<<<dim3(1024, BATCH), 256, 0, stream>>>(mask, m1);
  dilate_s2_k<64, 32><<<dim3(128, BATCH), 256, 0, stream>>>(m1, m2);
  dilate_s2_k<32, 16><<<dim3(16, BATCH), 256, 0, stream>>>(m2, m3);
  dilate_s2_k<16, 8><<<dim3(2, BATCH), 256, 0, stream>>>(m3, m4);

  // conv blocks (MFMA)
  conv1_mfma_k<128><<<dim3(262144 / 128, BATCH), 256, 0, stream>>>(xmh, wf1, b1, m1, h1);
  conv_mfma_k<64, 128, 64, 32, 64, 128, 2, 2><<<dim3(32768 / 64, 1, BATCH), 256, 0, stream>>>(h1, wf2, b2, m2, h2);
  conv_mfma_k<128, 256, 32, 16, 64, 128, 2, 2><<<dim3(4096 / 64, 2, BATCH), 256, 0, stream>>>(h2, wf3, b3, m3, h3);
  conv_mfma_k<256, 512, 16, 8, 16, 128, 1, 4><<<dim3(512 / 16, 4, BATCH), 256, 0, stream>>>(h3, wf4, b4, m4, h4);

  // pool + leaky relu
  pool_k<<<dim3(8, BATCH), 256, 0, stream>>>(h4, outp);
}

// Round 3
// 528.043 us; speedup vs baseline: 6.2410x; 1.0886x over previous
//
#include <hip/hip_runtime.h>

typedef _Float16 f16;
typedef _Float16 half4 __attribute__((ext_vector_type(4)));
typedef _Float16 half8 __attribute__((ext_vector_type(8)));
typedef float f32x4 __attribute__((ext_vector_type(4)));

#define BATCH 4

// ===================== weight prep =====================
// generic: w[co][ci][27] f32 -> w27[k][co][ci] f16
__global__ __launch_bounds__(256) void wprep_k(const float* __restrict__ w,
                                               f16* __restrict__ w27, int COUT, int CIN) {
  int idx = blockIdx.x * 256 + threadIdx.x;
  int total = COUT * CIN * 27;
  if (idx >= total) return;
  int k = idx % 27;
  int t = idx / 27;
  int ci = t % CIN;
  int co = t / CIN;
  w27[((size_t)k * COUT + co) * CIN + ci] = (f16)w[idx];
}

// conv1: w[64][3][27] f32 -> w1f[co][128] f16, q = k*4 + ci (ci==3 or k>=27 -> 0)
__global__ __launch_bounds__(256) void wprep1_k(const float* __restrict__ w,
                                                f16* __restrict__ wf) {
  int idx = blockIdx.x * 256 + threadIdx.x;   // 64*128
  if (idx >= 64 * 128) return;
  int q = idx & 127, co = idx >> 7;
  int k = q >> 2, ci = q & 3;
  float v = (ci < 3 && k < 27) ? w[(co * 3 + ci) * 27 + k] : 0.f;
  wf[idx] = (f16)v;
}

// xc[b][v][4] = mask-active ? x[b][ci][v] : 0 (f16, ch3 = 0)
__global__ __launch_bounds__(256) void xmask_k(const float* __restrict__ x,
                                               const int* __restrict__ mask,
                                               f16* __restrict__ xc) {
  const int D3 = 262144;
  int v = blockIdx.x * 256 + threadIdx.x;
  int b = blockIdx.y;
  bool act = mask[(size_t)b * D3 + v] < 1;
  const float* xb = x + (size_t)b * 3 * D3 + v;
  half4 o;
  o[0] = act ? (f16)xb[0] : (f16)0.f;
  o[1] = act ? (f16)xb[D3] : (f16)0.f;
  o[2] = act ? (f16)xb[2 * D3] : (f16)0.f;
  o[3] = (f16)0.f;
  *reinterpret_cast<half4*>(xc + ((size_t)b * D3 + v) * 4) = o;
}

// ===================== mask pyramid: separable dilation (u8, 4 voxels/thread) =====================
// pass W: from int mask -> aw (u8 0/1 dilated along w)
__global__ __launch_bounds__(256) void dil_w_k(const int* __restrict__ mask,
                                               unsigned char* __restrict__ aw) {
  const int D3 = 262144;
  int t = blockIdx.x * 256 + threadIdx.x;     // B*D3/4 threads
  int b = t >> 16;
  int v = (t & 65535) * 4;
  int w0 = v & 63;
  const int* mb = mask + (size_t)b * D3;
  int a[6];
  a[0] = (w0 > 0) ? (mb[v - 1] < 1) : 0;
  #pragma unroll
  for (int i = 0; i < 4; i++) a[i + 1] = mb[v + i] < 1;
  a[5] = (w0 < 60) ? (mb[v + 4] < 1) : 0;
  unsigned int o = 0;
  #pragma unroll
  for (int i = 0; i < 4; i++)
    o |= ((unsigned)(a[i] | a[i + 1] | a[i + 2])) << (8 * i);
  *reinterpret_cast<unsigned int*>(aw + (size_t)b * D3 + v) = o;
}

// pass H / pass D: u8 -> u8, or of 3 u32 at stride
template<int STRIDE, int DIMSHIFT>
__global__ __launch_bounds__(256) void dil_hd_k(const unsigned char* __restrict__ ai,
                                                unsigned char* __restrict__ ao) {
  const int D3 = 262144;
  int t = blockIdx.x * 256 + threadIdx.x;
  int b = t >> 16;
  int v = (t & 65535) * 4;
  int c = (v >> DIMSHIFT) & 63;
  const unsigned char* ib = ai + (size_t)b * D3;
  unsigned int m = *reinterpret_cast<const unsigned int*>(ib + v);
  if (c > 0)  m |= *reinterpret_cast<const unsigned int*>(ib + v - STRIDE);
  if (c < 63) m |= *reinterpret_cast<const unsigned int*>(ib + v + STRIDE);
  *reinterpret_cast<unsigned int*>(ao + (size_t)b * D3 + v) = m;
}

template<int DIN, int DOUT>
__global__ __launch_bounds__(256) void dilate_s2_k(const unsigned char* __restrict__ mi,
                                                   unsigned char* __restrict__ mo) {
  const int Do3 = DOUT * DOUT * DOUT;
  int v = blockIdx.x * 256 + threadIdx.x;
  if (v >= Do3) return;
  int b = blockIdx.y;
  int ow = v % DOUT, t = v / DOUT, oh = t % DOUT, od = t / DOUT;
  const unsigned char* ib = mi + (size_t)b * DIN * DIN * DIN;
  int act = 0;
  for (int kd = 0; kd < 3; kd++) { int id = od * 2 - 1 + kd; if ((unsigned)id >= (unsigned)DIN) continue;
    for (int kh = 0; kh < 3; kh++) { int ih = oh * 2 - 1 + kh; if ((unsigned)ih >= (unsigned)DIN) continue;
      for (int kw = 0; kw < 3; kw++) { int iw = ow * 2 - 1 + kw; if ((unsigned)iw >= (unsigned)DIN) continue;
        act |= ib[((size_t)id * DIN + ih) * DIN + iw];
      } } }
  mo[(size_t)b * Do3 + v] = (unsigned char)(act ? 1 : 0);
}

// ===================== conv1 via MFMA (vectorized 4-ch gather) =====================
// A = gather(xc) [BM][128], q = kslot*4+ci; B = w1f [64][128]; C -> h1 [v][64]
template<int BM>
__global__ __launch_bounds__(256) void conv1_mfma_k(const f16* __restrict__ xc,
                                                    const f16* __restrict__ w1f,
                                                    const float* __restrict__ bias,
                                                    const unsigned char* __restrict__ mo,
                                                    f16* __restrict__ out) {
  const int D = 64, D3 = D * D * D, COUT = 64;
  constexpr int K = 128, LD = K + 8;
  constexpr int WM = 2, WN = 2;
  constexpr int MF = BM / (16 * WM), NF = 64 / (16 * WN);
  __shared__ __align__(16) f16 As[BM][LD];
  __shared__ __align__(16) f16 Bs[64][LD];

  const int tid = threadIdx.x, lane = tid & 63, wave = tid >> 6;
  const int wm = wave >> 1, wn = wave & 1;
  const int v0 = blockIdx.x * BM;
  const int b = blockIdx.y;
  const f16* xb = xc + (size_t)b * D3 * 4;

  // stage B (coalesced)
  for (int c = tid; c < 64 * (K / 8); c += 256) {
    int row = c >> 4, cc = c & 15;
    *reinterpret_cast<half8*>(&Bs[row][cc * 8]) =
        *reinterpret_cast<const half8*>(w1f + row * K + cc * 8);
  }
  // stage A: per-(row,kslot) 8B gather; lanes cover consecutive rows -> coalesced
  {
    const int row = tid & (BM - 1);
    const int v = v0 + row;
    const int ow = v & 63, oh = (v >> 6) & 63, od = v >> 12;
    for (int e = tid; e < 32 * BM; e += 256) {
      int kslot = e / BM;
      half4 val = {};
      if (kslot < 27) {
        int kd = kslot / 9, r2 = kslot - kd * 9, kh = r2 / 3, kw = r2 - kh * 3;
        int id = od - 1 + kd, ih = oh - 1 + kh, iw = ow - 1 + kw;
        if ((unsigned)id < (unsigned)D && (unsigned)ih < (unsigned)D && (unsigned)iw < (unsigned)D)
          val = *reinterpret_cast<const half4*>(xb + (size_t)((id * D + ih) * D + iw) * 4);
      }
      *reinterpret_cast<half4*>(&As[row][kslot * 4]) = val;
    }
  }
  __syncthreads();

  f32x4 acc[MF][NF] = {};
  const int chanoff = (lane >> 4) << 3;
  const int arow = wm * MF * 16 + (lane & 15);
  const int brow = wn * NF * 16 + (lane & 15);
  #pragma unroll
  for (int q0 = 0; q0 < K; q0 += 32) {
    half8 a[MF], bb[NF];
    #pragma unroll
    for (int mf = 0; mf < MF; mf++)
      a[mf] = *reinterpret_cast<const half8*>(&As[arow + mf * 16][q0 + chanoff]);
    #pragma unroll
    for (int nf = 0; nf < NF; nf++)
      bb[nf] = *reinterpret_cast<const half8*>(&Bs[brow + nf * 16][q0 + chanoff]);
    #pragma unroll
    for (int mf = 0; mf < MF; mf++)
      #pragma unroll
      for (int nf = 0; nf < NF; nf++)
        acc[mf][nf] = __builtin_amdgcn_mfma_f32_16x16x32_f16(a[mf], bb[nf], acc[mf][nf], 0, 0, 0);
  }

  // epilogue
  const unsigned char* mb = mo + (size_t)b * D3;
  f16* ob = out + (size_t)b * D3 * COUT;
  float bv[NF];
  #pragma unroll
  for (int nf = 0; nf < NF; nf++) bv[nf] = bias[wn * NF * 16 + nf * 16 + (lane & 15)];
  #pragma unroll
  for (int mf = 0; mf < MF; mf++) {
    #pragma unroll
    for (int r = 0; r < 4; r++) {
      int v = v0 + wm * MF * 16 + mf * 16 + ((lane >> 4) << 2) + r;
      bool act = mb[v] != 0;
      #pragma unroll
      for (int nf = 0; nf < NF; nf++) {
        int co = wn * NF * 16 + nf * 16 + (lane & 15);
        float val = acc[mf][nf][r] + bv[nf];
        val = act ? (val > 0.f ? val : 0.f) : 0.f;
        ob[(size_t)v * COUT + co] = (f16)val;
      }
    }
  }
}

// ===================== generic stride-2 conv via MFMA =====================
template<int CIN, int COUT, int DIN, int DOUT, int BM, int BN, int WM, int WN>
__global__ __launch_bounds__(WM * WN * 64) void conv_mfma_k(const f16* __restrict__ in,
                                                            const f16* __restrict__ w27,
                                                            const float* __restrict__ bias,
                                                            const unsigned char* __restrict__ mo,
                                                            f16* __restrict__ out) {
  constexpr int MF = BM / (16 * WM);
  constexpr int NF = BN / (16 * WN);
  constexpr int THREADS = WM * WN * 64;
  constexpr int LD = CIN + 8;
  constexpr int D3o = DOUT * DOUT * DOUT;
  constexpr int LOGD = (DOUT == 32) ? 5 : ((DOUT == 16) ? 4 : 3);

  __shared__ __align__(16) f16 As[BM][LD];
  __shared__ __align__(16) f16 Bs[BN][LD];

  const int tid = threadIdx.x, lane = tid & 63, wave = tid >> 6;
  const int wm = wave / WN, wn = wave % WN;
  const int v0 = blockIdx.x * BM;
  const int co0 = blockIdx.y * BN;
  const int b = blockIdx.z;
  const f16* ib = in + (size_t)b * DIN * DIN * DIN * CIN;

  f32x4 acc[MF][NF] = {};

  const int chanoff = (lane >> 4) << 3;
  const int arow = wm * MF * 16 + (lane & 15);
  const int brow = wn * NF * 16 + (lane & 15);

  for (int k = 0; k < 27; k++) {
    int kd = k / 9, r2 = k - kd * 9, kh = r2 / 3, kw = r2 - kh * 3;
    constexpr int CA = BM * CIN / 8;
    for (int c = tid; c < CA; c += THREADS) {
      int row = c / (CIN / 8), cc = c & (CIN / 8 - 1);
      int v = v0 + row;
      int ow = v & (DOUT - 1), oh = (v >> LOGD) & (DOUT - 1), od = v >> (2 * LOGD);
      int id = 2 * od - 1 + kd, ih = 2 * oh - 1 + kh, iw = 2 * ow - 1 + kw;
      half8 val = {};
      if ((unsigned)id < (unsigned)DIN && (unsigned)ih < (unsigned)DIN && (unsigned)iw < (unsigned)DIN)
        val = *reinterpret_cast<const half8*>(ib + (((size_t)id * DIN + ih) * DIN + iw) * CIN + cc * 8);
      *reinterpret_cast<half8*>(&As[row][cc * 8]) = val;
    }
    const f16* wk = w27 + ((size_t)k * COUT + co0) * CIN;
    constexpr int CB = BN * CIN / 8;
    for (int c = tid; c < CB; c += THREADS) {
      int row = c / (CIN / 8), cc = c & (CIN / 8 - 1);
      *reinterpret_cast<half8*>(&Bs[row][cc * 8]) =
          *reinterpret_cast<const half8*>(wk + (size_t)row * CIN + cc * 8);
    }
    __syncthreads();
    #pragma unroll
    for (int ci0 = 0; ci0 < CIN; ci0 += 32) {
      half8 a[MF], bb[NF];
      #pragma unroll
      for (int mf = 0; mf < MF; mf++)
        a[mf] = *reinterpret_cast<const half8*>(&As[arow + mf * 16][ci0 + chanoff]);
      #pragma unroll
      for (int nf = 0; nf < NF; nf++)
        bb[nf] = *reinterpret_cast<const half8*>(&Bs[brow + nf * 16][ci0 + chanoff]);
      #pragma unroll
      for (int mf = 0; mf < MF; mf++)
        #pragma unroll
        for (int nf = 0; nf < NF; nf++)
          acc[mf][nf] = __builtin_amdgcn_mfma_f32_16x16x32_f16(a[mf], bb[nf], acc[mf][nf], 0, 0, 0);
    }
    __syncthreads();
  }

  const unsigned char* mb = mo + (size_t)b * D3o;
  f16* ob = out + (size_t)b * D3o * COUT;
  float bv[NF];
  #pragma unroll
  for (int nf = 0; nf < NF; nf++) bv[nf] = bias[co0 + wn * NF * 16 + nf * 16 + (lane & 15)];
  #pragma unroll
  for (int mf = 0; mf < MF; mf++) {
    #pragma unroll
    for (int r = 0; r < 4; r++) {
      int v = v0 + wm * MF * 16 + mf * 16 + ((lane >> 4) << 2) + r;
      bool act = mb[v] != 0;
      #pragma unroll
      for (int nf = 0; nf < NF; nf++) {
        int co = co0 + wn * NF * 16 + nf * 16 + (lane & 15);
        float val = acc[mf][nf][r] + bv[nf];
        val = act ? (val > 0.f ? val : 0.f) : 0.f;
        ob[(size_t)v * COUT + co] = (f16)val;
      }
    }
  }
}

// ===================== max pool + leaky relu =====================
__global__ __launch_bounds__(256) void pool_k(const f16* __restrict__ h4,
                                              float* __restrict__ outp) {
  __shared__ float red[4][64];
  int b = blockIdx.y;
  int cl = threadIdx.x & 63;
  int co = blockIdx.x * 64 + cl;
  int vg = threadIdx.x >> 6;
  const f16* p = h4 + (size_t)b * 512 * 512;
  float m = 0.f;
  for (int v = vg * 128; v < vg * 128 + 128; v++) m = fmaxf(m, (float)p[(size_t)v * 512 + co]);
  red[vg][cl] = m;
  __syncthreads();
  if (threadIdx.x < 64) {
    m = fmaxf(fmaxf(red[0][threadIdx.x], red[1][threadIdx.x]),
              fmaxf(red[2][threadIdx.x], red[3][threadIdx.x]));
    float r = (m >= 0.f) ? m : 0.2f * m;
    outp[b * 512 + blockIdx.x * 64 + threadIdx.x] = r;
  }
}

extern "C" void kernel_launch(void* const* d_in, const int* in_sizes, int n_in,
                              void* d_out, int out_size, void* d_ws, size_t ws_size,
                              hipStream_t stream) {
  const float* x    = (const float*)d_in[0];
  const int*   mask = (const int*)d_in[1];
  const float* w1 = (const float*)d_in[2];
  const float* b1 = (const float*)d_in[3];
  const float* w2 = (const float*)d_in[4];
  const float* b2 = (const float*)d_in[5];
  const float* w3 = (const float*)d_in[6];
  const float* b3 = (const float*)d_in[7];
  const float* w4 = (const float*)d_in[8];
  const float* b4 = (const float*)d_in[9];
  float* outp = (float*)d_out;

  char* ws = (char*)d_ws;
  size_t off = 0;
  auto alloc = [&](size_t bytes) -> char* {
    char* p = ws + off;
    off = (off + bytes + 255) & ~(size_t)255;
    return p;
  };
  f16* wf1 = (f16*)alloc((size_t)64 * 128 * 2);
  f16* wf2 = (f16*)alloc((size_t)27 * 128 * 64 * 2);
  f16* wf3 = (f16*)alloc((size_t)27 * 256 * 128 * 2);
  f16* wf4 = (f16*)alloc((size_t)27 * 512 * 256 * 2);
  f16* xc  = (f16*)alloc((size_t)BATCH * 262144 * 4 * 2);
  unsigned char* aw = (unsigned char*)alloc((size_t)BATCH * 262144);
  unsigned char* ah = (unsigned char*)alloc((size_t)BATCH * 262144);
  unsigned char* m1 = (unsigned char*)alloc((size_t)BATCH * 262144);
  unsigned char* m2 = (unsigned char*)alloc((size_t)BATCH * 32768);
  unsigned char* m3 = (unsigned char*)alloc((size_t)BATCH * 4096);
  unsigned char* m4 = (unsigned char*)alloc((size_t)BATCH * 512);
  f16* h1 = (f16*)alloc((size_t)BATCH * 262144 * 64 * 2);
  f16* h2 = (f16*)alloc((size_t)BATCH * 32768 * 128 * 2);
  f16* h3 = (f16*)alloc((size_t)BATCH * 4096 * 256 * 2);
  f16* h4 = (f16*)alloc((size_t)BATCH * 512 * 512 * 2);
  if (off > ws_size) return;

  // weight / input prep
  wprep1_k<<<dim3((64 * 128 + 255) / 256), 256, 0, stream>>>(w1, wf1);
  wprep_k<<<dim3((128 * 64 * 27 + 255) / 256), 256, 0, stream>>>(w2, wf2, 128, 64);
  wprep_k<<<dim3((256 * 128 * 27 + 255) / 256), 256, 0, stream>>>(w3, wf3, 256, 128);
  wprep_k<<<dim3((512 * 256 * 27 + 255) / 256), 256, 0, stream>>>(w4, wf4, 512, 256);
  xmask_k<<<dim3(1024, BATCH), 256, 0, stream>>>(x, mask, xc);

  // mask pyramid: separable dilation at D=64, then small stride-2 dilations
  dil_w_k<<<dim3(BATCH * 65536 / 256), 256, 0, stream>>>(mask, aw);
  dil_hd_k<64, 6><<<dim3(BATCH * 65536 / 256), 256, 0, stream>>>(aw, ah);
  dil_hd_k<4096, 12><<<dim3(BATCH * 65536 / 256), 256, 0, stream>>>(ah, m1);
  dilate_s2_k<64, 32><<<dim3(128, BATCH), 256, 0, stream>>>(m1, m2);
  dilate_s2_k<32, 16><<<dim3(16, BATCH), 256, 0, stream>>>(m2, m3);
  dilate_s2_k<16, 8><<<dim3(2, BATCH), 256, 0, stream>>>(m3, m4);

  // conv blocks (MFMA)
  conv1_mfma_k<128><<<dim3(262144 / 128, BATCH), 256, 0, stream>>>(xc, wf1, b1, m1, h1);
  conv_mfma_k<64, 128, 64, 32, 128, 128, 2, 2><<<dim3(32768 / 128, 1, BATCH), 256, 0, stream>>>(h1, wf2, b2, m2, h2);
  conv_mfma_k<128, 256, 32, 16, 64, 128, 2, 2><<<dim3(4096 / 64, 2, BATCH), 256, 0, stream>>>(h2, wf3, b3, m3, h3);
  conv_mfma_k<256, 512, 16, 8, 16, 128, 1, 4><<<dim3(512 / 16, 4, BATCH), 256, 0, stream>>>(h3, wf4, b4, m4, h4);

  // pool + leaky relu
  pool_k<<<dim3(8, BATCH), 256, 0, stream>>>(h4, outp);
}

// Round 4
// 351.943 us; speedup vs baseline: 9.3638x; 1.5004x over previous
//
#include <hip/hip_runtime.h>

typedef _Float16 f16;
typedef _Float16 half4 __attribute__((ext_vector_type(4)));
typedef _Float16 half8 __attribute__((ext_vector_type(8)));
typedef float f32x4 __attribute__((ext_vector_type(4)));

#define BATCH 4

// async global -> LDS, 16B per lane; dest = wave-uniform base + lane*16
__device__ __forceinline__ void gload16(const void* g, void* l) {
  __builtin_amdgcn_global_load_lds((const __attribute__((address_space(1))) unsigned int*)g,
                                   (__attribute__((address_space(3))) unsigned int*)l, 16, 0, 0);
}

// ===================== zero page =====================
__global__ __launch_bounds__(256) void zero_k(unsigned int* __restrict__ z) {
  z[threadIdx.x] = 0u;   // 1KB
}

// ===================== weight prep =====================
// generic: w[co][ci][27] f32 -> w27[k][co][ci] f16
__global__ __launch_bounds__(256) void wprep_k(const float* __restrict__ w,
                                               f16* __restrict__ w27, int COUT, int CIN) {
  int idx = blockIdx.x * 256 + threadIdx.x;
  int total = COUT * CIN * 27;
  if (idx >= total) return;
  int k = idx % 27;
  int t = idx / 27;
  int ci = t % CIN;
  int co = t / CIN;
  w27[((size_t)k * COUT + co) * CIN + ci] = (f16)w[idx];
}

// conv1: w[64][3][27] f32 -> w1f[co][128] f16, q = k*4 + ci (ci==3 or k>=27 -> 0)
__global__ __launch_bounds__(256) void wprep1_k(const float* __restrict__ w,
                                                f16* __restrict__ wf) {
  int idx = blockIdx.x * 256 + threadIdx.x;   // 64*128
  if (idx >= 64 * 128) return;
  int q = idx & 127, co = idx >> 7;
  int k = q >> 2, ci = q & 3;
  float v = (ci < 3 && k < 27) ? w[(co * 3 + ci) * 27 + k] : 0.f;
  wf[idx] = (f16)v;
}

// xc[b][v][4] = mask-active ? x[b][ci][v] : 0 (f16, ch3 = 0)
__global__ __launch_bounds__(256) void xmask_k(const float* __restrict__ x,
                                               const int* __restrict__ mask,
                                               f16* __restrict__ xc) {
  const int D3 = 262144;
  int v = blockIdx.x * 256 + threadIdx.x;
  int b = blockIdx.y;
  bool act = mask[(size_t)b * D3 + v] < 1;
  const float* xb = x + (size_t)b * 3 * D3 + v;
  half4 o;
  o[0] = act ? (f16)xb[0] : (f16)0.f;
  o[1] = act ? (f16)xb[D3] : (f16)0.f;
  o[2] = act ? (f16)xb[2 * D3] : (f16)0.f;
  o[3] = (f16)0.f;
  *reinterpret_cast<half4*>(xc + ((size_t)b * D3 + v) * 4) = o;
}

// ===================== mask pyramid: separable dilation =====================
__global__ __launch_bounds__(256) void dil_w_k(const int* __restrict__ mask,
                                               unsigned char* __restrict__ aw) {
  const int D3 = 262144;
  int t = blockIdx.x * 256 + threadIdx.x;
  int b = t >> 16;
  int v = (t & 65535) * 4;
  int w0 = v & 63;
  const int* mb = mask + (size_t)b * D3;
  int a[6];
  a[0] = (w0 > 0) ? (mb[v - 1] < 1) : 0;
  #pragma unroll
  for (int i = 0; i < 4; i++) a[i + 1] = mb[v + i] < 1;
  a[5] = (w0 < 60) ? (mb[v + 4] < 1) : 0;
  unsigned int o = 0;
  #pragma unroll
  for (int i = 0; i < 4; i++)
    o |= ((unsigned)(a[i] | a[i + 1] | a[i + 2])) << (8 * i);
  *reinterpret_cast<unsigned int*>(aw + (size_t)b * D3 + v) = o;
}

template<int STRIDE, int DIMSHIFT>
__global__ __launch_bounds__(256) void dil_hd_k(const unsigned char* __restrict__ ai,
                                                unsigned char* __restrict__ ao) {
  const int D3 = 262144;
  int t = blockIdx.x * 256 + threadIdx.x;
  int b = t >> 16;
  int v = (t & 65535) * 4;
  int c = (v >> DIMSHIFT) & 63;
  const unsigned char* ib = ai + (size_t)b * D3;
  unsigned int m = *reinterpret_cast<const unsigned int*>(ib + v);
  if (c > 0)  m |= *reinterpret_cast<const unsigned int*>(ib + v - STRIDE);
  if (c < 63) m |= *reinterpret_cast<const unsigned int*>(ib + v + STRIDE);
  *reinterpret_cast<unsigned int*>(ao + (size_t)b * D3 + v) = m;
}

template<int DIN, int DOUT>
__global__ __launch_bounds__(256) void dilate_s2_k(const unsigned char* __restrict__ mi,
                                                   unsigned char* __restrict__ mo) {
  const int Do3 = DOUT * DOUT * DOUT;
  int v = blockIdx.x * 256 + threadIdx.x;
  if (v >= Do3) return;
  int b = blockIdx.y;
  int ow = v % DOUT, t = v / DOUT, oh = t % DOUT, od = t / DOUT;
  const unsigned char* ib = mi + (size_t)b * DIN * DIN * DIN;
  int act = 0;
  for (int kd = 0; kd < 3; kd++) { int id = od * 2 - 1 + kd; if ((unsigned)id >= (unsigned)DIN) continue;
    for (int kh = 0; kh < 3; kh++) { int ih = oh * 2 - 1 + kh; if ((unsigned)ih >= (unsigned)DIN) continue;
      for (int kw = 0; kw < 3; kw++) { int iw = ow * 2 - 1 + kw; if ((unsigned)iw >= (unsigned)DIN) continue;
        act |= ib[((size_t)id * DIN + ih) * DIN + iw];
      } } }
  mo[(size_t)b * Do3 + v] = (unsigned char)(act ? 1 : 0);
}

// ===================== conv1 via MFMA (single-stage) =====================
template<int BM>
__global__ __launch_bounds__(256) void conv1_mfma_k(const f16* __restrict__ xc,
                                                    const f16* __restrict__ w1f,
                                                    const float* __restrict__ bias,
                                                    const unsigned char* __restrict__ mo,
                                                    f16* __restrict__ out) {
  const int D = 64, D3 = D * D * D, COUT = 64;
  constexpr int K = 128, LD = K + 8;
  constexpr int WM = 2, WN = 2;
  constexpr int MF = BM / (16 * WM), NF = 64 / (16 * WN);
  __shared__ __align__(16) f16 As[BM][LD];
  __shared__ __align__(16) f16 Bs[64][LD];

  const int tid = threadIdx.x, lane = tid & 63, wave = tid >> 6;
  const int wm = wave >> 1, wn = wave & 1;
  const int v0 = blockIdx.x * BM;
  const int b = blockIdx.y;
  const f16* xb = xc + (size_t)b * D3 * 4;

  for (int c = tid; c < 64 * (K / 8); c += 256) {
    int row = c >> 4, cc = c & 15;
    *reinterpret_cast<half8*>(&Bs[row][cc * 8]) =
        *reinterpret_cast<const half8*>(w1f + row * K + cc * 8);
  }
  {
    const int row = tid & (BM - 1);
    const int v = v0 + row;
    const int ow = v & 63, oh = (v >> 6) & 63, od = v >> 12;
    for (int e = tid; e < 32 * BM; e += 256) {
      int kslot = e / BM;
      half4 val = {};
      if (kslot < 27) {
        int kd = kslot / 9, r2 = kslot - kd * 9, kh = r2 / 3, kw = r2 - kh * 3;
        int id = od - 1 + kd, ih = oh - 1 + kh, iw = ow - 1 + kw;
        if ((unsigned)id < (unsigned)D && (unsigned)ih < (unsigned)D && (unsigned)iw < (unsigned)D)
          val = *reinterpret_cast<const half4*>(xb + (size_t)((id * D + ih) * D + iw) * 4);
      }
      *reinterpret_cast<half4*>(&As[row][kslot * 4]) = val;
    }
  }
  __syncthreads();

  f32x4 acc[MF][NF] = {};
  const int chanoff = (lane >> 4) << 3;
  const int arow = wm * MF * 16 + (lane & 15);
  const int brow = wn * NF * 16 + (lane & 15);
  #pragma unroll
  for (int q0 = 0; q0 < K; q0 += 32) {
    half8 a[MF], bb[NF];
    #pragma unroll
    for (int mf = 0; mf < MF; mf++)
      a[mf] = *reinterpret_cast<const half8*>(&As[arow + mf * 16][q0 + chanoff]);
    #pragma unroll
    for (int nf = 0; nf < NF; nf++)
      bb[nf] = *reinterpret_cast<const half8*>(&Bs[brow + nf * 16][q0 + chanoff]);
    #pragma unroll
    for (int mf = 0; mf < MF; mf++)
      #pragma unroll
      for (int nf = 0; nf < NF; nf++)
        acc[mf][nf] = __builtin_amdgcn_mfma_f32_16x16x32_f16(a[mf], bb[nf], acc[mf][nf], 0, 0, 0);
  }

  const unsigned char* mb = mo + (size_t)b * D3;
  f16* ob = out + (size_t)b * D3 * COUT;
  float bv[NF];
  #pragma unroll
  for (int nf = 0; nf < NF; nf++) bv[nf] = bias[wn * NF * 16 + nf * 16 + (lane & 15)];
  #pragma unroll
  for (int mf = 0; mf < MF; mf++) {
    #pragma unroll
    for (int r = 0; r < 4; r++) {
      int v = v0 + wm * MF * 16 + mf * 16 + ((lane >> 4) << 2) + r;
      bool act = mb[v] != 0;
      #pragma unroll
      for (int nf = 0; nf < NF; nf++) {
        int co = wn * NF * 16 + nf * 16 + (lane & 15);
        float val = acc[mf][nf][r] + bv[nf];
        val = act ? (val > 0.f ? val : 0.f) : 0.f;
        ob[(size_t)v * COUT + co] = (f16)val;
      }
    }
  }
}

// ===================== stride-2 conv, 2-phase pipelined MFMA =====================
// in [B][DIN^3][CIN] f16, w27 [27][COUT][CIN] f16, out [B][DOUT^3][COUT] f16
// Double-buffered LDS staged via global_load_lds(16B); XOR chunk swizzle c^=(row&7)
// applied on the per-lane GLOBAL source and on the ds_read address (both-sides rule).
template<int CIN, int COUT, int DIN, int DOUT, int BM, int BN, int WM, int WN, int SWZ>
__global__ __launch_bounds__(WM * WN * 64) void conv_mfma2_k(const f16* __restrict__ in,
                                                             const f16* __restrict__ w27,
                                                             const float* __restrict__ bias,
                                                             const unsigned char* __restrict__ mo,
                                                             const f16* __restrict__ zpage,
                                                             f16* __restrict__ out) {
  constexpr int NW = WM * WN;
  constexpr int MF = BM / (16 * WM), NF = BN / (16 * WN);
  constexpr int ROWB = CIN * 2;          // bytes per LDS row
  constexpr int CHUNKS = ROWB / 16;      // 16B chunks per row
  constexpr int RPI = 64 / CHUNKS;       // rows per gload instr (wave = 1024B)
  constexpr int A_IW = BM / RPI / NW;    // gload instrs per wave (A)
  constexpr int B_IW = BN / RPI / NW;
  constexpr int D3o = DOUT * DOUT * DOUT;
  constexpr int LOGD = (DOUT == 32) ? 5 : ((DOUT == 16) ? 4 : 3);

  __shared__ __align__(16) char As[2][BM * ROWB];
  __shared__ __align__(16) char Bs[2][BN * ROWB];

  const int tid = threadIdx.x, lane = tid & 63, wave = tid >> 6;
  const int wm = wave / WN, wn = wave % WN;
  int bx = blockIdx.x;
  if (SWZ) {                              // XCD-aware swizzle (gridDim.x % 8 == 0)
    int cpx = gridDim.x >> 3;
    bx = (bx & 7) * cpx + (bx >> 3);
  }
  const int v0 = bx * BM, co0 = blockIdx.y * BN, b = blockIdx.z;
  const char* ib = (const char*)(in + (size_t)b * DIN * DIN * DIN * CIN);

  // ---- per-lane staging precompute ----
  const int lrow = lane / CHUNKS;         // row within gload group
  const int lchunk = lane % CHUNKS;       // LDS slot this lane fills
  int a_od[A_IW], a_oh[A_IW], a_ow[A_IW], a_cb[A_IW];
  #pragma unroll
  for (int i = 0; i < A_IW; i++) {
    int r = (wave * A_IW + i) * RPI + lrow;
    int v = v0 + r;
    a_ow[i] = v & (DOUT - 1);
    a_oh[i] = (v >> LOGD) & (DOUT - 1);
    a_od[i] = v >> (2 * LOGD);
    a_cb[i] = (lchunk ^ (r & 7)) * 16;    // pre-swizzled source chunk byte offset
  }
  size_t b_ob[B_IW];
  #pragma unroll
  for (int i = 0; i < B_IW; i++) {
    int r = (wave * B_IW + i) * RPI + lrow;
    int g = lchunk ^ (r & 7);
    b_ob[i] = ((size_t)(co0 + r) * CIN + g * 8) * 2;   // bytes into k-slice
  }

  auto stage = [&](int buf, int k) {
    int kd = k / 9, r2 = k - kd * 9, kh = r2 / 3, kw = r2 - kh * 3;
    #pragma unroll
    for (int i = 0; i < A_IW; i++) {
      int id = 2 * a_od[i] - 1 + kd, ih = 2 * a_oh[i] - 1 + kh, iw = 2 * a_ow[i] - 1 + kw;
      bool inb = (unsigned)id < (unsigned)DIN && (unsigned)ih < (unsigned)DIN &&
                 (unsigned)iw < (unsigned)DIN;
      const char* src = inb
          ? ib + ((size_t)(id * DIN + ih) * DIN + iw) * ROWB + a_cb[i]
          : (const char*)zpage;
      gload16(src, &As[buf][(wave * A_IW + i) * 1024]);
    }
    const char* wk = (const char*)w27 + (size_t)k * COUT * CIN * 2;
    #pragma unroll
    for (int i = 0; i < B_IW; i++)
      gload16(wk + b_ob[i], &Bs[buf][(wave * B_IW + i) * 1024]);
  };

  f32x4 acc[MF][NF] = {};
  const int ll = lane & 15, lh = lane >> 4;
  const int ra0 = wm * MF * 16 + ll;
  const int rb0 = wn * NF * 16 + ll;
  const int rswa = ra0 & 7;               // (ra0 + mf*16) & 7 == ra0 & 7
  const int rswb = rb0 & 7;

  stage(0, 0);
  __syncthreads();                        // implicit vmcnt(0) drain
  int cur = 0;
  for (int k = 0; k < 27; k++) {
    if (k < 26) stage(cur ^ 1, k + 1);    // prefetch overlaps this k's MFMA
    #pragma unroll
    for (int ci0 = 0; ci0 < CIN; ci0 += 32) {
      const int q = (ci0 >> 3) + lh;      // logical 16B chunk of the frag
      half8 a[MF], bb[NF];
      #pragma unroll
      for (int mf = 0; mf < MF; mf++)
        a[mf] = *reinterpret_cast<const half8*>(
            &As[cur][(ra0 + mf * 16) * ROWB + ((q ^ rswa) * 16)]);
      #pragma unroll
      for (int nf = 0; nf < NF; nf++)
        bb[nf] = *reinterpret_cast<const half8*>(
            &Bs[cur][(rb0 + nf * 16) * ROWB + ((q ^ rswb) * 16)]);
      #pragma unroll
      for (int mf = 0; mf < MF; mf++)
        #pragma unroll
        for (int nf = 0; nf < NF; nf++)
          acc[mf][nf] = __builtin_amdgcn_mfma_f32_16x16x32_f16(a[mf], bb[nf], acc[mf][nf], 0, 0, 0);
    }
    __syncthreads();                      // drains prefetch vmcnt + syncs LDS reads
    cur ^= 1;
  }

  // ---- epilogue ----
  const unsigned char* mb = mo + (size_t)b * D3o;
  f16* ob = out + (size_t)b * D3o * COUT;
  float bv[NF];
  #pragma unroll
  for (int nf = 0; nf < NF; nf++) bv[nf] = bias[co0 + wn * NF * 16 + nf * 16 + ll];
  #pragma unroll
  for (int mf = 0; mf < MF; mf++) {
    #pragma unroll
    for (int r = 0; r < 4; r++) {
      int v = v0 + wm * MF * 16 + mf * 16 + (lh << 2) + r;
      bool act = mb[v] != 0;
      #pragma unroll
      for (int nf = 0; nf < NF; nf++) {
        int co = co0 + wn * NF * 16 + nf * 16 + ll;
        float val = acc[mf][nf][r] + bv[nf];
        val = act ? (val > 0.f ? val : 0.f) : 0.f;
        ob[(size_t)v * COUT + co] = (f16)val;
      }
    }
  }
}

// ===================== max pool + leaky relu =====================
__global__ __launch_bounds__(256) void pool_k(const f16* __restrict__ h4,
                                              float* __restrict__ outp) {
  __shared__ float red[4][64];
  int b = blockIdx.y;
  int cl = threadIdx.x & 63;
  int co = blockIdx.x * 64 + cl;
  int vg = threadIdx.x >> 6;
  const f16* p = h4 + (size_t)b * 512 * 512;
  float m = 0.f;
  for (int v = vg * 128; v < vg * 128 + 128; v++) m = fmaxf(m, (float)p[(size_t)v * 512 + co]);
  red[vg][cl] = m;
  __syncthreads();
  if (threadIdx.x < 64) {
    m = fmaxf(fmaxf(red[0][threadIdx.x], red[1][threadIdx.x]),
              fmaxf(red[2][threadIdx.x], red[3][threadIdx.x]));
    float r = (m >= 0.f) ? m : 0.2f * m;
    outp[b * 512 + blockIdx.x * 64 + threadIdx.x] = r;
  }
}

extern "C" void kernel_launch(void* const* d_in, const int* in_sizes, int n_in,
                              void* d_out, int out_size, void* d_ws, size_t ws_size,
                              hipStream_t stream) {
  const float* x    = (const float*)d_in[0];
  const int*   mask = (const int*)d_in[1];
  const float* w1 = (const float*)d_in[2];
  const float* b1 = (const float*)d_in[3];
  const float* w2 = (const float*)d_in[4];
  const float* b2 = (const float*)d_in[5];
  const float* w3 = (const float*)d_in[6];
  const float* b3 = (const float*)d_in[7];
  const float* w4 = (const float*)d_in[8];
  const float* b4 = (const float*)d_in[9];
  float* outp = (float*)d_out;

  char* ws = (char*)d_ws;
  size_t off = 0;
  auto alloc = [&](size_t bytes) -> char* {
    char* p = ws + off;
    off = (off + bytes + 255) & ~(size_t)255;
    return p;
  };
  f16* wf1 = (f16*)alloc((size_t)64 * 128 * 2);
  f16* wf2 = (f16*)alloc((size_t)27 * 128 * 64 * 2);
  f16* wf3 = (f16*)alloc((size_t)27 * 256 * 128 * 2);
  f16* wf4 = (f16*)alloc((size_t)27 * 512 * 256 * 2);
  f16* zpg = (f16*)alloc(1024);
  f16* xc  = (f16*)alloc((size_t)BATCH * 262144 * 4 * 2);
  unsigned char* aw = (unsigned char*)alloc((size_t)BATCH * 262144);
  unsigned char* ah = (unsigned char*)alloc((size_t)BATCH * 262144);
  unsigned char* m1 = (unsigned char*)alloc((size_t)BATCH * 262144);
  unsigned char* m2 = (unsigned char*)alloc((size_t)BATCH * 32768);
  unsigned char* m3 = (unsigned char*)alloc((size_t)BATCH * 4096);
  unsigned char* m4 = (unsigned char*)alloc((size_t)BATCH * 512);
  f16* h1 = (f16*)alloc((size_t)BATCH * 262144 * 64 * 2);
  f16* h2 = (f16*)alloc((size_t)BATCH * 32768 * 128 * 2);
  f16* h3 = (f16*)alloc((size_t)BATCH * 4096 * 256 * 2);
  f16* h4 = (f16*)alloc((size_t)BATCH * 512 * 512 * 2);
  if (off > ws_size) return;

  // prep
  zero_k<<<dim3(1), 256, 0, stream>>>((unsigned int*)zpg);
  wprep1_k<<<dim3((64 * 128 + 255) / 256), 256, 0, stream>>>(w1, wf1);
  wprep_k<<<dim3((128 * 64 * 27 + 255) / 256), 256, 0, stream>>>(w2, wf2, 128, 64);
  wprep_k<<<dim3((256 * 128 * 27 + 255) / 256), 256, 0, stream>>>(w3, wf3, 256, 128);
  wprep_k<<<dim3((512 * 256 * 27 + 255) / 256), 256, 0, stream>>>(w4, wf4, 512, 256);
  xmask_k<<<dim3(1024, BATCH), 256, 0, stream>>>(x, mask, xc);

  // mask pyramid
  dil_w_k<<<dim3(BATCH * 65536 / 256), 256, 0, stream>>>(mask, aw);
  dil_hd_k<64, 6><<<dim3(BATCH * 65536 / 256), 256, 0, stream>>>(aw, ah);
  dil_hd_k<4096, 12><<<dim3(BATCH * 65536 / 256), 256, 0, stream>>>(ah, m1);
  dilate_s2_k<64, 32><<<dim3(128, BATCH), 256, 0, stream>>>(m1, m2);
  dilate_s2_k<32, 16><<<dim3(16, BATCH), 256, 0, stream>>>(m2, m3);
  dilate_s2_k<16, 8><<<dim3(2, BATCH), 256, 0, stream>>>(m3, m4);

  // conv blocks
  conv1_mfma_k<128><<<dim3(262144 / 128, BATCH), 256, 0, stream>>>(xc, wf1, b1, m1, h1);
  conv_mfma2_k<64, 128, 64, 32, 128, 128, 2, 2, 1>
      <<<dim3(256, 1, BATCH), 256, 0, stream>>>(h1, wf2, b2, m2, zpg, h2);
  conv_mfma2_k<128, 256, 32, 16, 64, 64, 2, 2, 0>
      <<<dim3(64, 4, BATCH), 256, 0, stream>>>(h2, wf3, b3, m3, zpg, h3);
  conv_mfma2_k<256, 512, 16, 8, 64, 64, 2, 2, 0>
      <<<dim3(8, 8, BATCH), 256, 0, stream>>>(h3, wf4, b4, m4, zpg, h4);

  // pool + leaky relu
  pool_k<<<dim3(8, BATCH), 256, 0, stream>>>(h4, outp);
}